// Round 13
// baseline (122.287 us; speedup 1.0000x reference)
//
#include <hip/hip_runtime.h>
#include <hip/hip_bf16.h>
#include <stdint.h>

typedef __attribute__((ext_vector_type(8))) short bf16x8;
typedef __attribute__((ext_vector_type(4))) float f32x4;
typedef __attribute__((ext_vector_type(4))) unsigned int u32x4;
typedef __attribute__((ext_vector_type(2))) unsigned int u32x2;
typedef unsigned short u16;
typedef unsigned int u32;
typedef unsigned char u8;
typedef unsigned long long u64;

#define N_NODES 8192
#define N_EDGES 1024
#define F_DIM   256

__device__ __forceinline__ u16 f2bf(float f) {
    union { float f; u32 u; } v; v.f = f;
    u32 u = v.u;
    u = (u + 0x7FFFu + ((u >> 16) & 1u)) >> 16;   // round-nearest-even
    return (u16)u;
}

// async 16B global -> LDS (wave-uniform LDS base + lane*16; per-lane global src)
__device__ __forceinline__ void async16(const u16* g, u16* l) {
    __builtin_amdgcn_global_load_lds(
        (const __attribute__((address_space(1))) u32*)(const void*)g,
        (__attribute__((address_space(3))) u32*)(void*)l, 16, 0, 0);
}

// expand 8 mask bits -> bf16x8 of {1.0, 0.0} (elem j = bit j)
__device__ __forceinline__ bf16x8 expand8(u32 byte) {
    union { u32 u[4]; bf16x8 v; } r;
#pragma unroll
    for (int i = 0; i < 4; ++i)
        r.u[i] = (((byte >> (2 * i)) & 1u) ? 0x3F80u : 0u)
               | (((byte >> (2 * i + 1)) & 1u) ? 0x3F800000u : 0u);
    return r.v;
}

// ---------------------------------------------------------------------------
// prep v5 — ONE pass over H (33.5 MB, the only cold HBM read) + FUSED gemmZ.
// Block = 32 rows, 8 waves x 4 rows. Produces:
//   dv[n]          row popcounts (shfl reduce)
//   HbTs[seg][e]   node-chunk-major bitmask (gemmM2 A)
//   HbN[we][n]     edge-word-major bitmask (gemmOUT A)
//   Zt[j][n]       bf16( sum_f Xs[n][f]*W[j][f] ), Xs = bf16(X*rsqrt(dv)):
//                  gemmZ fused IN-BLOCK (Z rows depend only on this block's
//                  X rows + shared W). Wave wv owns j-slab [wv*32,+32):
//                  A-frags from LDS-staged Xls, B-frags cvt'd from fp32 W
//                  (256 KB, L2-resident across 256 blocks). Same MFMA K-order
//                  as R12's gemmZ -> bit-identical Z. Xsb/Wb buffers deleted.
// Zero atomics, zero memsets anywhere in the pipeline.
// ---------------------------------------------------------------------------
__global__ __launch_bounds__(512) void prep(
    const float* __restrict__ H, const float* __restrict__ X,
    const float* __restrict__ W,
    float* __restrict__ dv, u32* __restrict__ HbTs, u32* __restrict__ HbN,
    u16* __restrict__ Zt) {
    __shared__ u16 hmask[32][68];     // 4.25 KB (pad 68: 2-way max on reads)
    __shared__ u16 Xls[32][264];      // 16.9 KB scaled bf16 X rows (pad 264)
    const int tid = threadIdx.x;
    const int wv = tid >> 6;
    const int lane = tid & 63;
    const int blk = blockIdx.x;
    const int n0 = blk * 32 + wv * 4;

    f32x4 hv[4][4], xv[4];
#pragma unroll
    for (int r = 0; r < 4; ++r) {
        const int n = n0 + r;
#pragma unroll
        for (int q = 0; q < 4; ++q)
            hv[r][q] = *(const f32x4*)(&H[(size_t)n * N_EDGES + q * 256 + lane * 4]);
        xv[r] = *(const f32x4*)(&X[(size_t)n * F_DIM + lane * 4]);
    }

#pragma unroll
    for (int r = 0; r < 4; ++r) {
        const int n = n0 + r;
        u32 m16 = 0u;
#pragma unroll
        for (int q = 0; q < 4; ++q)
#pragma unroll
            for (int j = 0; j < 4; ++j)
                m16 |= ((hv[r][q][j] != 0.f) ? 1u : 0u) << (q * 4 + j);
        hmask[wv * 4 + r][lane] = (u16)m16;
        u32 s = (u32)__popc(m16);
#pragma unroll
        for (int d = 1; d < 64; d <<= 1) s += __shfl_xor(s, d, 64);
        if (lane == 0) dv[n] = (float)s;
        const float sc = rsqrtf((float)s);
        u32x2 pk;
        pk[0] = (u32)f2bf(xv[r][0] * sc) | ((u32)f2bf(xv[r][1] * sc) << 16);
        pk[1] = (u32)f2bf(xv[r][2] * sc) | ((u32)f2bf(xv[r][3] * sc) << 16);
        *(u32x2*)(&Xls[wv * 4 + r][lane * 4]) = pk;
    }
    __syncthreads();
    // HbTs node-chunk-major: thread t -> edges 2t, 2t+1 (4 KB coalesced row)
    {
        u32x2 st;
#pragma unroll
        for (int eo = 0; eo < 2; ++eo) {
            const int e = tid * 2 + eo;
            const int widx = (e & 255) >> 2;
            const int bit = ((e >> 8) << 2) + (e & 3);
            u32 w = 0u;
#pragma unroll
            for (int r = 0; r < 32; ++r)
                w |= (u32)((hmask[r][widx] >> bit) & 1u) << r;
            st[eo] = w;
        }
        *(u32x2*)(&HbTs[(size_t)blk * N_EDGES + tid * 2]) = st;
    }
    // HbN edge-word-major: bit o of word (n, we) = H[n][we*32+o].
    {
        const int r = tid & 31;          // node-local: coalesced stores
        const int wec = tid >> 5;        // 0..15; words wec and wec+16
#pragma unroll
        for (int wo = 0; wo < 2; ++wo) {
            const int we = wec + wo * 16;
            const int q = we >> 3, l0 = (we & 7) * 8;
            const u32x2 a = *(const u32x2*)(&hmask[r][l0]);
            const u32x2 b2 = *(const u32x2*)(&hmask[r][l0 + 4]);
            const u32 sh = q * 4;
            u32 w = ((a[0] >> sh) & 0xFu)
                  | (((a[0] >> (16 + sh)) & 0xFu) << 4)
                  | (((a[1] >> sh) & 0xFu) << 8)
                  | (((a[1] >> (16 + sh)) & 0xFu) << 12)
                  | (((b2[0] >> sh) & 0xFu) << 16)
                  | (((b2[0] >> (16 + sh)) & 0xFu) << 20)
                  | (((b2[1] >> sh) & 0xFu) << 24)
                  | (((b2[1] >> (16 + sh)) & 0xFu) << 28);
            HbN[(size_t)we * N_NODES + blk * 32 + r] = w;
        }
    }
    // ---- fused gemmZ: Z[32 n][256 j], wave wv owns j in [wv*32, wv*32+32) ----
    {
        const int row16 = lane & 15, quad = lane >> 4;
        f32x4 acc[2][2] = {};
#pragma unroll
        for (int ks = 0; ks < 8; ++ks) {
            bf16x8 af[2];
#pragma unroll
            for (int tm = 0; tm < 2; ++tm)
                af[tm] = *(const bf16x8*)(&Xls[tm * 16 + row16][ks * 32 + quad * 8]);
#pragma unroll
            for (int tn = 0; tn < 2; ++tn) {
                const int j = wv * 32 + tn * 16 + row16;
                const f32x4 w0 = *(const f32x4*)(&W[(size_t)j * F_DIM + ks * 32 + quad * 8]);
                const f32x4 w1 = *(const f32x4*)(&W[(size_t)j * F_DIM + ks * 32 + quad * 8 + 4]);
                union { u32x4 u; bf16x8 v; } bu;
                bu.u[0] = (u32)f2bf(w0[0]) | ((u32)f2bf(w0[1]) << 16);
                bu.u[1] = (u32)f2bf(w0[2]) | ((u32)f2bf(w0[3]) << 16);
                bu.u[2] = (u32)f2bf(w1[0]) | ((u32)f2bf(w1[1]) << 16);
                bu.u[3] = (u32)f2bf(w1[2]) | ((u32)f2bf(w1[3]) << 16);
#pragma unroll
                for (int tm = 0; tm < 2; ++tm)
                    acc[tm][tn] = __builtin_amdgcn_mfma_f32_16x16x32_bf16(
                        af[tm], bu.v, acc[tm][tn], 0, 0, 0);
            }
        }
#pragma unroll
        for (int tm = 0; tm < 2; ++tm)
#pragma unroll
            for (int tn = 0; tn < 2; ++tn) {
                const int j = wv * 32 + tn * 16 + row16;
                u32x2 pk;
                pk[0] = (u32)f2bf(acc[tm][tn][0]) | ((u32)f2bf(acc[tm][tn][1]) << 16);
                pk[1] = (u32)f2bf(acc[tm][tn][2]) | ((u32)f2bf(acc[tm][tn][3]) << 16);
                *(u32x2*)(&Zt[(size_t)j * N_NODES + blk * 32 + tm * 16 + quad * 4]) = pk;
            }
    }
}

// ---------------------------------------------------------------------------
// gemmM2 — M2t[j][e] = bf16( (1/de) * sum_n H[n][e] * Z[n][j] ). R12 VERBATIM
// (passed). 256 blocks x 8 waves, wave-private async16 dbuf, counted vmcnt(4),
// in-loop popcount de, j-group==XCD, el-major coalesced epilogue.
// ---------------------------------------------------------------------------
__global__ __launch_bounds__(512) void gemmM2(
    const u16* __restrict__ Zt, const u32* __restrict__ HbTs,
    u16* __restrict__ M2t) {
    __shared__ __align__(16) u8 smem[65536];
    __shared__ float cnts[8][2][16];
    const int tid = threadIdx.x;
    const int wv = tid >> 6, lane = tid & 63;
    const int f0 = ((int)blockIdx.x & 7) * 32;   // j-group == XCD
    const int e0 = ((int)blockIdx.x >> 3) * 32;
    const int row16 = lane & 15, quad = lane >> 4;
    const int srow = lane & 15, schunk = lane >> 4;
    u16* myBs = (u16*)(smem + wv * 8192);
    const int kbase = wv * 1024;

    f32x4 acc[2][2] = {};
    u32 cnt0 = 0, cnt1 = 0;
    u32 wA[2][2], wB[2][2];

    auto STAGE = [&](int it, int buf) {
        __builtin_amdgcn_sched_barrier(0);
        const int k0 = kbase + it * 64;
#pragma unroll
        for (int tn = 0; tn < 2; ++tn)
#pragma unroll
            for (int ks = 0; ks < 2; ++ks)
                async16(Zt + (size_t)(f0 + tn * 16 + srow) * N_NODES + k0 + ks * 32 + schunk * 8,
                        myBs + buf * 2048 + (tn * 2 + ks) * 512);
    };
    auto LOADW = [&](int it, u32 (&w)[2][2]) {
        const int k0 = kbase + it * 64;
#pragma unroll
        for (int tm = 0; tm < 2; ++tm)
#pragma unroll
            for (int ks = 0; ks < 2; ++ks)
                w[tm][ks] = HbTs[(size_t)((k0 >> 5) + ks) * N_EDGES + e0 + tm * 16 + row16];
    };
    auto COMPUTE = [&](int buf, u32 (&w)[2][2]) {
        asm volatile("s_waitcnt vmcnt(4)" ::: "memory");
        __builtin_amdgcn_sched_barrier(0);
#pragma unroll
        for (int ks = 0; ks < 2; ++ks) {
            bf16x8 bfr[2];
#pragma unroll
            for (int tn = 0; tn < 2; ++tn)
                bfr[tn] = *(const bf16x8*)(myBs + buf * 2048 + (tn * 2 + ks) * 512 + lane * 8);
#pragma unroll
            for (int tm = 0; tm < 2; ++tm) {
                const u32 byte = (w[tm][ks] >> (quad * 8)) & 0xFFu;
                if (tm == 0) cnt0 += (u32)__popc(byte); else cnt1 += (u32)__popc(byte);
                const bf16x8 af = expand8(byte);
#pragma unroll
                for (int tn = 0; tn < 2; ++tn)
                    acc[tm][tn] = __builtin_amdgcn_mfma_f32_16x16x32_bf16(
                        af, bfr[tn], acc[tm][tn], 0, 0, 0);
            }
        }
    };

    STAGE(0, 0);
    LOADW(0, wA);
    for (int i = 0; i < 8; ++i) {
        STAGE(2 * i + 1, 1);
        LOADW(2 * i + 1, wB);
        COMPUTE(0, wA);
        const int nxt = (2 * i + 2 < 16) ? (2 * i + 2) : 15;
        STAGE(nxt, 0);
        LOADW(nxt, wA);
        COMPUTE(1, wB);
    }

    cnt0 += __shfl_down(cnt0, 32, 64); cnt0 += __shfl_down(cnt0, 16, 64);
    cnt1 += __shfl_down(cnt1, 32, 64); cnt1 += __shfl_down(cnt1, 16, 64);
    if (lane < 16) {
        cnts[wv][0][lane] = (float)cnt0;
        cnts[wv][1][lane] = (float)cnt1;
    }
    __syncthreads();
    {
        float* redf = (float*)smem;
        float* my = &redf[(size_t)(wv * 64 + lane) * 17];
#pragma unroll
        for (int tm = 0; tm < 2; ++tm)
#pragma unroll
            for (int tn = 0; tn < 2; ++tn)
#pragma unroll
                for (int r = 0; r < 4; ++r)
                    my[tm * 8 + tn * 4 + r] = acc[tm][tn][r];
    }
    __syncthreads();
    {
        const float* redf = (const float*)smem;
#pragma unroll
        for (int h = 0; h < 2; ++h) {
            const int idx = tid + h * 512;
            const int fl = idx >> 5, el = idx & 31;   // el-major: coalesced M2t
            const int tm = el >> 4, q = (el >> 2) & 3, r = el & 3;
            const int tn = fl >> 4, r16 = fl & 15;
            const int srcl = q * 16 + r16;
            const int j = tm * 8 + tn * 4 + r;
            float s = 0.f, de = 0.f;
#pragma unroll
            for (int w = 0; w < 8; ++w) {
                s += redf[(size_t)(w * 64 + srcl) * 17 + j];
                de += cnts[w][tm][el & 15];
            }
            M2t[(size_t)(f0 + fl) * N_EDGES + e0 + el] = f2bf(s / de);
        }
    }
}

// ---------------------------------------------------------------------------
// gemmOUT — out[n][j] = rsqrt(dv[n]) * sum_e H[n][e]*M2[e][j] + b[j] as a
// bitmask-MFMA over K=1024 edges. R12 VERBATIM (passed). Block = 256n x 32j;
// B staged once (64 KB padded), A-masks double-buffered coalesced u32 loads.
// ---------------------------------------------------------------------------
__global__ __launch_bounds__(512) void gemmOUT(
    const u16* __restrict__ M2t, const u32* __restrict__ HbN,
    const float* __restrict__ dv, const float* __restrict__ bias,
    float* __restrict__ out) {
    __shared__ __align__(16) u16 Bs[32 * 1028];   // pad 1028: b64 reads ~2-way
    const int tid = threadIdx.x;
    const int wv = tid >> 6, lane = tid & 63;
    const int row16 = lane & 15, quad = lane >> 4;
    const int j0 = ((int)blockIdx.x & 7) * 32;    // j-group == XCD
    const int ng = ((int)blockIdx.x >> 3) * 256 + wv * 32;

#pragma unroll
    for (int rr = 0; rr < 4; ++rr) {
        const int jr = wv * 4 + rr;
#pragma unroll
        for (int c = 0; c < 2; ++c)
            async16(M2t + (size_t)(j0 + jr) * N_EDGES + c * 512 + lane * 8,
                    &Bs[jr * 1028 + c * 512]);
    }
    __syncthreads();   // compiler drains vmcnt before barrier

    f32x4 acc[2][2] = {};
    u32 wA[2][2], wB[2][2];
    auto LOADW = [&](int it, u32 (&w)[2][2]) {
#pragma unroll
        for (int tm = 0; tm < 2; ++tm)
#pragma unroll
            for (int ks = 0; ks < 2; ++ks)
                w[tm][ks] = HbN[(size_t)(it * 2 + ks) * N_NODES + ng + tm * 16 + row16];
    };
    auto COMPUTE = [&](int it, u32 (&w)[2][2]) {
#pragma unroll
        for (int ks = 0; ks < 2; ++ks) {
            bf16x8 bfr[2];
#pragma unroll
            for (int tn = 0; tn < 2; ++tn) {
                const int base = (tn * 16 + row16) * 1028 + it * 64 + ks * 32 + quad * 8;
                union { u32x2 lo_hi[2]; bf16x8 v; } u;
                u.lo_hi[0] = *(const u32x2*)(&Bs[base]);
                u.lo_hi[1] = *(const u32x2*)(&Bs[base + 4]);
                bfr[tn] = u.v;
            }
#pragma unroll
            for (int tm = 0; tm < 2; ++tm) {
                const u32 byte = (w[tm][ks] >> (quad * 8)) & 0xFFu;
                const bf16x8 af = expand8(byte);
#pragma unroll
                for (int tn = 0; tn < 2; ++tn)
                    acc[tm][tn] = __builtin_amdgcn_mfma_f32_16x16x32_bf16(
                        af, bfr[tn], acc[tm][tn], 0, 0, 0);
            }
        }
    };

    LOADW(0, wA);
    for (int i = 0; i < 8; ++i) {
        LOADW(2 * i + 1, wB);
        COMPUTE(2 * i, wA);
        const int nxt = (2 * i + 2 < 16) ? (2 * i + 2) : 15;
        LOADW(nxt, wA);
        COMPUTE(2 * i + 1, wB);
    }

#pragma unroll
    for (int tm = 0; tm < 2; ++tm)
#pragma unroll
        for (int tn = 0; tn < 2; ++tn) {
            const int col = j0 + tn * 16 + row16;
            const float bc = bias[col];
#pragma unroll
            for (int r = 0; r < 4; ++r) {
                const int n = ng + tm * 16 + quad * 4 + r;
                out[(size_t)n * F_DIM + col] = acc[tm][tn][r] * rsqrtf(dv[n]) + bc;
            }
        }
}

// ---------------------------------------------------------------------------
extern "C" void kernel_launch(void* const* d_in, const int* in_sizes, int n_in,
                              void* d_out, int out_size, void* d_ws, size_t ws_size,
                              hipStream_t stream) {
    (void)in_sizes; (void)n_in; (void)out_size; (void)ws_size;
    const float* X = (const float*)d_in[0];   // [8192 x 256]
    const float* H = (const float*)d_in[1];   // [8192 x 1024]
    const float* W = (const float*)d_in[2];   // [256 x 256]
    const float* b = (const float*)d_in[3];   // [256]
    float* out = (float*)d_out;               // [8192 x 256] fp32

    char* ws = (char*)d_ws;
    float* dv   = (float*)(ws);                // 32 KB  [8192]
    u32*   HbTs = (u32*)(ws + 0x10000);        // 1 MB   [256 seg][1024 e]
    u32*   HbN  = (u32*)(ws + 0x110000);       // 1 MB   [32 we][8192 n]
    u16*   Zt   = (u16*)(ws + 0x210000);       // 4 MB   [256 j][8192 n] bf16
    u16*   M2t  = (u16*)(ws + 0x610000);       // 512 KB [256 j][1024 e] bf16

    prep<<<256, 512, 0, stream>>>(H, X, W, dv, HbTs, HbN, Zt);
    gemmM2<<<256, 512, 0, stream>>>(Zt, HbTs, M2t);
    gemmOUT<<<256, 512, 0, stream>>>(M2t, HbN, dv, b, out);
}

// Round 15
// 122.098 us; speedup vs baseline: 1.0016x; 1.0016x over previous
//
#include <hip/hip_runtime.h>
#include <hip/hip_bf16.h>
#include <stdint.h>

typedef __attribute__((ext_vector_type(8))) short bf16x8;
typedef __attribute__((ext_vector_type(4))) float f32x4;
typedef __attribute__((ext_vector_type(4))) unsigned int u32x4;
typedef __attribute__((ext_vector_type(2))) unsigned int u32x2;
typedef unsigned short u16;
typedef unsigned int u32;
typedef unsigned char u8;
typedef unsigned long long u64;

#define N_NODES 8192
#define N_EDGES 1024
#define F_DIM   256

__device__ __forceinline__ u16 f2bf(float f) {
    union { float f; u32 u; } v; v.f = f;
    u32 u = v.u;
    u = (u + 0x7FFFu + ((u >> 16) & 1u)) >> 16;   // round-nearest-even
    return (u16)u;
}

// async 16B global -> LDS (wave-uniform LDS base + lane*16; per-lane global src)
__device__ __forceinline__ void async16(const u16* g, u16* l) {
    __builtin_amdgcn_global_load_lds(
        (const __attribute__((address_space(1))) u32*)(const void*)g,
        (__attribute__((address_space(3))) u32*)(void*)l, 16, 0, 0);
}

// expand 8 mask bits -> bf16x8 of {1.0, 0.0} (elem j = bit j)
__device__ __forceinline__ bf16x8 expand8(u32 byte) {
    union { u32 u[4]; bf16x8 v; } r;
#pragma unroll
    for (int i = 0; i < 4; ++i)
        r.u[i] = (((byte >> (2 * i)) & 1u) ? 0x3F80u : 0u)
               | (((byte >> (2 * i + 1)) & 1u) ? 0x3F800000u : 0u);
    return r.v;
}

// ---------------------------------------------------------------------------
// prep v6 — ONE pass over H (33.5 MB) + fused gemmZ. 1024 THREADS (16 waves
// x 2 rows) -> 4 waves/SIMD: 2x latency hiding for the HBM load batch vs R13.
// Producers: HbTs one edge/thread, HbN one word/thread (coalesced u32
// stores). Fused gemmZ: wave wv owns j-slab [wv*16,+16), same ks/tm MFMA
// order as R13 -> bit-identical Zt. Zero atomics, zero memsets.
// ---------------------------------------------------------------------------
__global__ __launch_bounds__(1024) void prep(
    const float* __restrict__ H, const float* __restrict__ X,
    const float* __restrict__ W,
    float* __restrict__ dv, u32* __restrict__ HbTs, u32* __restrict__ HbN,
    u16* __restrict__ Zt) {
    __shared__ u16 hmask[32][68];     // 4.25 KB (pad 68: 2-way max on reads)
    __shared__ u16 Xls[32][264];      // 16.9 KB scaled bf16 X rows (pad 264)
    const int tid = threadIdx.x;
    const int wv = tid >> 6;          // 0..15
    const int lane = tid & 63;
    const int blk = blockIdx.x;
    const int n0 = blk * 32 + wv * 2;

    f32x4 hv[2][4], xv[2];
#pragma unroll
    for (int r = 0; r < 2; ++r) {
        const int n = n0 + r;
#pragma unroll
        for (int q = 0; q < 4; ++q)
            hv[r][q] = *(const f32x4*)(&H[(size_t)n * N_EDGES + q * 256 + lane * 4]);
        xv[r] = *(const f32x4*)(&X[(size_t)n * F_DIM + lane * 4]);
    }

#pragma unroll
    for (int r = 0; r < 2; ++r) {
        const int n = n0 + r;
        u32 m16 = 0u;
#pragma unroll
        for (int q = 0; q < 4; ++q)
#pragma unroll
            for (int j = 0; j < 4; ++j)
                m16 |= ((hv[r][q][j] != 0.f) ? 1u : 0u) << (q * 4 + j);
        hmask[wv * 2 + r][lane] = (u16)m16;
        u32 s = (u32)__popc(m16);
#pragma unroll
        for (int d = 1; d < 64; d <<= 1) s += __shfl_xor(s, d, 64);
        if (lane == 0) dv[n] = (float)s;
        const float sc = rsqrtf((float)s);
        u32x2 pk;
        pk[0] = (u32)f2bf(xv[r][0] * sc) | ((u32)f2bf(xv[r][1] * sc) << 16);
        pk[1] = (u32)f2bf(xv[r][2] * sc) | ((u32)f2bf(xv[r][3] * sc) << 16);
        *(u32x2*)(&Xls[wv * 2 + r][lane * 4]) = pk;
    }
    __syncthreads();
    // HbTs node-chunk-major: ONE edge per thread, coalesced u32 store
    {
        const int e = tid;
        const int widx = (e & 255) >> 2;
        const int bit = ((e >> 8) << 2) + (e & 3);
        u32 w = 0u;
#pragma unroll
        for (int r = 0; r < 32; ++r)
            w |= (u32)((hmask[r][widx] >> bit) & 1u) << r;
        HbTs[(size_t)blk * N_EDGES + e] = w;
    }
    // HbN edge-word-major: ONE word per thread (bit o of (n,we) = H[n][we*32+o])
    {
        const int r = tid & 31;          // node-local: coalesced stores
        const int we = tid >> 5;         // 0..31
        const int q = we >> 3, l0 = (we & 7) * 8;
        const u32x2 a = *(const u32x2*)(&hmask[r][l0]);
        const u32x2 b2 = *(const u32x2*)(&hmask[r][l0 + 4]);
        const u32 sh = q * 4;
        u32 w = ((a[0] >> sh) & 0xFu)
              | (((a[0] >> (16 + sh)) & 0xFu) << 4)
              | (((a[1] >> sh) & 0xFu) << 8)
              | (((a[1] >> (16 + sh)) & 0xFu) << 12)
              | (((b2[0] >> sh) & 0xFu) << 16)
              | (((b2[0] >> (16 + sh)) & 0xFu) << 20)
              | (((b2[1] >> sh) & 0xFu) << 24)
              | (((b2[1] >> (16 + sh)) & 0xFu) << 28);
        HbN[(size_t)we * N_NODES + blk * 32 + r] = w;
    }
    // ---- fused gemmZ: Z[32 n][256 j], wave wv owns j in [wv*16, wv*16+16) ----
    {
        const int row16 = lane & 15, quad = lane >> 4;
        const int j = wv * 16 + row16;
        f32x4 acc[2] = {};
#pragma unroll
        for (int ks = 0; ks < 8; ++ks) {
            bf16x8 af[2];
#pragma unroll
            for (int tm = 0; tm < 2; ++tm)
                af[tm] = *(const bf16x8*)(&Xls[tm * 16 + row16][ks * 32 + quad * 8]);
            const f32x4 w0 = *(const f32x4*)(&W[(size_t)j * F_DIM + ks * 32 + quad * 8]);
            const f32x4 w1 = *(const f32x4*)(&W[(size_t)j * F_DIM + ks * 32 + quad * 8 + 4]);
            union { u32x4 u; bf16x8 v; } bu;
            bu.u[0] = (u32)f2bf(w0[0]) | ((u32)f2bf(w0[1]) << 16);
            bu.u[1] = (u32)f2bf(w0[2]) | ((u32)f2bf(w0[3]) << 16);
            bu.u[2] = (u32)f2bf(w1[0]) | ((u32)f2bf(w1[1]) << 16);
            bu.u[3] = (u32)f2bf(w1[2]) | ((u32)f2bf(w1[3]) << 16);
#pragma unroll
            for (int tm = 0; tm < 2; ++tm)
                acc[tm] = __builtin_amdgcn_mfma_f32_16x16x32_bf16(
                    af[tm], bu.v, acc[tm], 0, 0, 0);
        }
#pragma unroll
        for (int tm = 0; tm < 2; ++tm) {
            u32x2 pk;
            pk[0] = (u32)f2bf(acc[tm][0]) | ((u32)f2bf(acc[tm][1]) << 16);
            pk[1] = (u32)f2bf(acc[tm][2]) | ((u32)f2bf(acc[tm][3]) << 16);
            *(u32x2*)(&Zt[(size_t)j * N_NODES + blk * 32 + tm * 16 + quad * 4]) = pk;
        }
    }
}

// ---------------------------------------------------------------------------
// gemmM2 — M2t[j][e] = bf16( (1/de) * sum_n H[n][e] * Z[n][j] ). R13 with ONE
// fix: vmcnt(4) -> vmcnt(8). At each COMPUTE exactly 16 VMEM ops are
// outstanding (prev STAGE+LOADW = 8 old, next STAGE+LOADW = 8 new); waiting
// to 8 drains precisely the ops COMPUTE needs while the prefetch stays in
// flight — TRUE double-buffering (vmcnt(4) over-drained and serialized).
// ---------------------------------------------------------------------------
__global__ __launch_bounds__(512) void gemmM2(
    const u16* __restrict__ Zt, const u32* __restrict__ HbTs,
    u16* __restrict__ M2t) {
    __shared__ __align__(16) u8 smem[65536];
    __shared__ float cnts[8][2][16];
    const int tid = threadIdx.x;
    const int wv = tid >> 6, lane = tid & 63;
    const int f0 = ((int)blockIdx.x & 7) * 32;   // j-group == XCD
    const int e0 = ((int)blockIdx.x >> 3) * 32;
    const int row16 = lane & 15, quad = lane >> 4;
    const int srow = lane & 15, schunk = lane >> 4;
    u16* myBs = (u16*)(smem + wv * 8192);
    const int kbase = wv * 1024;

    f32x4 acc[2][2] = {};
    u32 cnt0 = 0, cnt1 = 0;
    u32 wA[2][2], wB[2][2];

    auto STAGE = [&](int it, int buf) {
        __builtin_amdgcn_sched_barrier(0);
        const int k0 = kbase + it * 64;
#pragma unroll
        for (int tn = 0; tn < 2; ++tn)
#pragma unroll
            for (int ks = 0; ks < 2; ++ks)
                async16(Zt + (size_t)(f0 + tn * 16 + srow) * N_NODES + k0 + ks * 32 + schunk * 8,
                        myBs + buf * 2048 + (tn * 2 + ks) * 512);
    };
    auto LOADW = [&](int it, u32 (&w)[2][2]) {
        const int k0 = kbase + it * 64;
#pragma unroll
        for (int tm = 0; tm < 2; ++tm)
#pragma unroll
            for (int ks = 0; ks < 2; ++ks)
                w[tm][ks] = HbTs[(size_t)((k0 >> 5) + ks) * N_EDGES + e0 + tm * 16 + row16];
    };
    auto COMPUTE = [&](int buf, u32 (&w)[2][2]) {
        asm volatile("s_waitcnt vmcnt(8)" ::: "memory");
        __builtin_amdgcn_sched_barrier(0);
#pragma unroll
        for (int ks = 0; ks < 2; ++ks) {
            bf16x8 bfr[2];
#pragma unroll
            for (int tn = 0; tn < 2; ++tn)
                bfr[tn] = *(const bf16x8*)(myBs + buf * 2048 + (tn * 2 + ks) * 512 + lane * 8);
#pragma unroll
            for (int tm = 0; tm < 2; ++tm) {
                const u32 byte = (w[tm][ks] >> (quad * 8)) & 0xFFu;
                if (tm == 0) cnt0 += (u32)__popc(byte); else cnt1 += (u32)__popc(byte);
                const bf16x8 af = expand8(byte);
#pragma unroll
                for (int tn = 0; tn < 2; ++tn)
                    acc[tm][tn] = __builtin_amdgcn_mfma_f32_16x16x32_bf16(
                        af, bfr[tn], acc[tm][tn], 0, 0, 0);
            }
        }
    };

    STAGE(0, 0);
    LOADW(0, wA);
    for (int i = 0; i < 8; ++i) {
        STAGE(2 * i + 1, 1);
        LOADW(2 * i + 1, wB);
        COMPUTE(0, wA);
        const int nxt = (2 * i + 2 < 16) ? (2 * i + 2) : 15;
        STAGE(nxt, 0);
        LOADW(nxt, wA);
        COMPUTE(1, wB);
    }

    cnt0 += __shfl_down(cnt0, 32, 64); cnt0 += __shfl_down(cnt0, 16, 64);
    cnt1 += __shfl_down(cnt1, 32, 64); cnt1 += __shfl_down(cnt1, 16, 64);
    if (lane < 16) {
        cnts[wv][0][lane] = (float)cnt0;
        cnts[wv][1][lane] = (float)cnt1;
    }
    __syncthreads();
    {
        float* redf = (float*)smem;
        float* my = &redf[(size_t)(wv * 64 + lane) * 17];
#pragma unroll
        for (int tm = 0; tm < 2; ++tm)
#pragma unroll
            for (int tn = 0; tn < 2; ++tn)
#pragma unroll
                for (int r = 0; r < 4; ++r)
                    my[tm * 8 + tn * 4 + r] = acc[tm][tn][r];
    }
    __syncthreads();
    {
        const float* redf = (const float*)smem;
#pragma unroll
        for (int h = 0; h < 2; ++h) {
            const int idx = tid + h * 512;
            const int fl = idx >> 5, el = idx & 31;   // el-major: coalesced M2t
            const int tm = el >> 4, q = (el >> 2) & 3, r = el & 3;
            const int tn = fl >> 4, r16 = fl & 15;
            const int srcl = q * 16 + r16;
            const int j = tm * 8 + tn * 4 + r;
            float s = 0.f, de = 0.f;
#pragma unroll
            for (int w = 0; w < 8; ++w) {
                s += redf[(size_t)(w * 64 + srcl) * 17 + j];
                de += cnts[w][tm][el & 15];
            }
            M2t[(size_t)(f0 + fl) * N_EDGES + e0 + el] = f2bf(s / de);
        }
    }
}

// ---------------------------------------------------------------------------
// gemmOUT — out[n][j] = rsqrt(dv[n]) * sum_e H[n][e]*M2[e][j] + b[j] as a
// bitmask-MFMA over K=1024 edges. R13 VERBATIM (passed twice).
// ---------------------------------------------------------------------------
__global__ __launch_bounds__(512) void gemmOUT(
    const u16* __restrict__ M2t, const u32* __restrict__ HbN,
    const float* __restrict__ dv, const float* __restrict__ bias,
    float* __restrict__ out) {
    __shared__ __align__(16) u16 Bs[32 * 1028];   // pad 1028: b64 reads ~2-way
    const int tid = threadIdx.x;
    const int wv = tid >> 6, lane = tid & 63;
    const int row16 = lane & 15, quad = lane >> 4;
    const int j0 = ((int)blockIdx.x & 7) * 32;    // j-group == XCD
    const int ng = ((int)blockIdx.x >> 3) * 256 + wv * 32;

#pragma unroll
    for (int rr = 0; rr < 4; ++rr) {
        const int jr = wv * 4 + rr;
#pragma unroll
        for (int c = 0; c < 2; ++c)
            async16(M2t + (size_t)(j0 + jr) * N_EDGES + c * 512 + lane * 8,
                    &Bs[jr * 1028 + c * 512]);
    }
    __syncthreads();   // compiler drains vmcnt before barrier

    f32x4 acc[2][2] = {};
    u32 wA[2][2], wB[2][2];
    auto LOADW = [&](int it, u32 (&w)[2][2]) {
#pragma unroll
        for (int tm = 0; tm < 2; ++tm)
#pragma unroll
            for (int ks = 0; ks < 2; ++ks)
                w[tm][ks] = HbN[(size_t)(it * 2 + ks) * N_NODES + ng + tm * 16 + row16];
    };
    auto COMPUTE = [&](int it, u32 (&w)[2][2]) {
#pragma unroll
        for (int ks = 0; ks < 2; ++ks) {
            bf16x8 bfr[2];
#pragma unroll
            for (int tn = 0; tn < 2; ++tn) {
                const int base = (tn * 16 + row16) * 1028 + it * 64 + ks * 32 + quad * 8;
                union { u32x2 lo_hi[2]; bf16x8 v; } u;
                u.lo_hi[0] = *(const u32x2*)(&Bs[base]);
                u.lo_hi[1] = *(const u32x2*)(&Bs[base + 4]);
                bfr[tn] = u.v;
            }
#pragma unroll
            for (int tm = 0; tm < 2; ++tm) {
                const u32 byte = (w[tm][ks] >> (quad * 8)) & 0xFFu;
                const bf16x8 af = expand8(byte);
#pragma unroll
                for (int tn = 0; tn < 2; ++tn)
                    acc[tm][tn] = __builtin_amdgcn_mfma_f32_16x16x32_bf16(
                        af, bfr[tn], acc[tm][tn], 0, 0, 0);
            }
        }
    };

    LOADW(0, wA);
    for (int i = 0; i < 8; ++i) {
        LOADW(2 * i + 1, wB);
        COMPUTE(2 * i, wA);
        const int nxt = (2 * i + 2 < 16) ? (2 * i + 2) : 15;
        LOADW(nxt, wA);
        COMPUTE(2 * i + 1, wB);
    }

#pragma unroll
    for (int tm = 0; tm < 2; ++tm)
#pragma unroll
        for (int tn = 0; tn < 2; ++tn) {
            const int col = j0 + tn * 16 + row16;
            const float bc = bias[col];
#pragma unroll
            for (int r = 0; r < 4; ++r) {
                const int n = ng + tm * 16 + quad * 4 + r;
                out[(size_t)n * F_DIM + col] = acc[tm][tn][r] * rsqrtf(dv[n]) + bc;
            }
        }
}

// ---------------------------------------------------------------------------
extern "C" void kernel_launch(void* const* d_in, const int* in_sizes, int n_in,
                              void* d_out, int out_size, void* d_ws, size_t ws_size,
                              hipStream_t stream) {
    (void)in_sizes; (void)n_in; (void)out_size; (void)ws_size;
    const float* X = (const float*)d_in[0];   // [8192 x 256]
    const float* H = (const float*)d_in[1];   // [8192 x 1024]
    const float* W = (const float*)d_in[2];   // [256 x 256]
    const float* b = (const float*)d_in[3];   // [256]
    float* out = (float*)d_out;               // [8192 x 256] fp32

    char* ws = (char*)d_ws;
    float* dv   = (float*)(ws);                // 32 KB  [8192]
    u32*   HbTs = (u32*)(ws + 0x10000);        // 1 MB   [256 seg][1024 e]
    u32*   HbN  = (u32*)(ws + 0x110000);       // 1 MB   [32 we][8192 n]
    u16*   Zt   = (u16*)(ws + 0x210000);       // 4 MB   [256 j][8192 n] bf16
    u16*   M2t  = (u16*)(ws + 0x610000);       // 512 KB [256 j][1024 e] bf16

    prep<<<256, 1024, 0, stream>>>(H, X, W, dv, HbTs, HbN, Zt);
    gemmM2<<<256, 512, 0, stream>>>(Zt, HbTs, M2t);
    gemmOUT<<<256, 512, 0, stream>>>(M2t, HbN, dv, b, out);
}